// Round 5
// baseline (298.487 us; speedup 1.0000x reference)
//
#include <hip/hip_runtime.h>
#include <hip/hip_bf16.h>

#define CC 16
#define LL 8192
#define SS 8191   // L-1
#define EE 512
#define HH 256
#define MM 128
#define TOPK 30

typedef __attribute__((ext_vector_type(8))) short short8;
typedef __attribute__((ext_vector_type(4))) float f32x4;
typedef __attribute__((ext_vector_type(4))) unsigned int u32x4;

static __device__ __forceinline__ unsigned short f2bf(float f) {
    unsigned u = __builtin_bit_cast(unsigned, f);
    u += 0x7FFFu + ((u >> 16) & 1u);   // RNE
    return (unsigned short)(u >> 16);
}

static __device__ __forceinline__ unsigned pk2(float lo, float hi) {
    __hip_bfloat162 t = __float22bfloat162_rn(float2{lo, hi});
    unsigned u;
    __builtin_memcpy(&u, &t, 4);
    return u;
}

// 8 f32 -> 8 bf16 via packed converts (v_cvt_pk_bf16_f32)
static __device__ __forceinline__ short8 cvt8(const float4 a, const float4 b) {
    u32x4 uv;
    uv[0] = pk2(a.x, a.y);
    uv[1] = pk2(a.z, a.w);
    uv[2] = pk2(b.x, b.y);
    uv[3] = pk2(b.z, b.w);
    return __builtin_bit_cast(short8, uv);
}

// ---------------- prep: W1 (E x H) -> W1T bf16 (H x E); W2 (H x M) -> W2T bf16 (M x H)
__global__ void prep_weights(const float* __restrict__ W1, const float* __restrict__ W2,
                             unsigned short* __restrict__ W1T, unsigned short* __restrict__ W2T)
{
    const int b = blockIdx.x, tid = threadIdx.x;
    if (b < 64) {
        const int e0 = b * 8, h = tid;
        short8 sv;
#pragma unroll
        for (int j = 0; j < 8; ++j)
            sv[j] = (short)f2bf(W1[(size_t)(e0 + j) * HH + h]);
        *(short8*)(void*)(W1T + (size_t)h * EE + e0) = sv;
    } else {
        const int h0 = (b - 64) * 16;
        if (tid < MM) {
            const int m = tid;
            short8 s0v, s1v;
#pragma unroll
            for (int j = 0; j < 8; ++j) {
                s0v[j] = (short)f2bf(W2[(size_t)(h0 + j) * MM + m]);
                s1v[j] = (short)f2bf(W2[(size_t)(h0 + 8 + j) * MM + m]);
            }
            *(short8*)(void*)(W2T + (size_t)m * HH + h0) = s0v;
            *(short8*)(void*)(W2T + (size_t)m * HH + h0 + 8) = s1v;
        }
    }
}

// ---------------- fused main kernel: 32 rows/block, 256 threads (4 waves)
// LDS 16.9KB: h[32][256] bf16 swizzled; after GEMM2 barrier, logits f32 [32][132] overwrite.
__global__ __launch_bounds__(256, 6)
void gene_router_kernel(const float* __restrict__ x,
                        const int*   __restrict__ mask,
                        const float* __restrict__ noise,
                        const unsigned short* __restrict__ W1T,
                        const float* __restrict__ b1,
                        const unsigned short* __restrict__ W2T,
                        const float* __restrict__ b2,
                        float* __restrict__ out,
                        float* __restrict__ outk)
{
    __shared__ float sLf[32 * 132];                 // 16896 B
    unsigned char* ldsb = (unsigned char*)sLf;

    const int tid = threadIdx.x;
    const int c   = blockIdx.y;
    const int s0  = blockIdx.x * 32;

    const int w    = tid >> 6;      // wave 0..3
    const int lane = tid & 63;
    const int lr   = lane & 15;
    const int kq   = lane >> 4;

    // ---- GEMM1: h[32][256] = relu(xs @ W1 + b1); A direct from global f32 ----
    f32x4 acc[2][4];
#pragma unroll
    for (int r = 0; r < 2; ++r)
#pragma unroll
        for (int n = 0; n < 4; ++n) acc[r][n] = (f32x4)0.0f;

    const float* xbase = x + ((size_t)c * LL + s0 + 1) * EE + kq * 8;
    const float* aptr[2];
#pragma unroll
    for (int r = 0; r < 2; ++r) {
        const int rloc = min(s0 + r * 16 + lr, SS - 1) - s0;   // clamp tail
        aptr[r] = xbase + (size_t)rloc * EE;
    }

    const int cw = w * 64;
#pragma unroll 2
    for (int ks = 0; ks < 16; ++ks) {
        short8 af[2];
#pragma unroll
        for (int r = 0; r < 2; ++r) {
            const float4 a0 = *(const float4*)(aptr[r] + ks * 32);
            const float4 a1 = *(const float4*)(aptr[r] + ks * 32 + 4);
            af[r] = cvt8(a0, a1);
        }
        short8 bf_[4];
#pragma unroll
        for (int n = 0; n < 4; ++n)
            bf_[n] = *(const short8*)(const void*)(W1T + (size_t)(cw + n * 16 + lr) * EE + ks * 32 + kq * 8);
#pragma unroll
        for (int r = 0; r < 2; ++r)
#pragma unroll
            for (int n = 0; n < 4; ++n)
                acc[r][n] = __builtin_amdgcn_mfma_f32_16x16x32_bf16(af[r], bf_[n], acc[r][n], 0, 0, 0);
    }

    // bias + relu -> h (bf16, XOR-swizzled rows) in ldsb[0,16K)
#pragma unroll
    for (int n = 0; n < 4; ++n) {
        const int colh = cw + n * 16 + lr;
        const float bb = b1[colh];
#pragma unroll
        for (int r = 0; r < 2; ++r)
#pragma unroll
            for (int q = 0; q < 4; ++q) {
                const int row = r * 16 + kq * 4 + q;
                const unsigned short hv = f2bf(fmaxf(acc[r][n][q] + bb, 0.0f));
                *(unsigned short*)(ldsb + row * 512 + ((colh * 2) ^ ((row & 7) << 4))) = hv;
            }
    }
    __syncthreads();

    // ---- GEMM2: logits[32][128] = h @ W2 ----
    f32x4 acc2[2][2];
#pragma unroll
    for (int r = 0; r < 2; ++r)
#pragma unroll
        for (int n = 0; n < 2; ++n) acc2[r][n] = (f32x4)0.0f;

    const int cw2 = w * 32;
#pragma unroll 2
    for (int ks = 0; ks < 8; ++ks) {
        short8 ah[2];
#pragma unroll
        for (int r = 0; r < 2; ++r) {
            const int row = r * 16 + lr;
            ah[r] = *(const short8*)(const void*)(ldsb + row * 512 + ((ks * 64 + kq * 16) ^ ((row & 7) << 4)));
        }
        short8 bw[2];
#pragma unroll
        for (int n = 0; n < 2; ++n)
            bw[n] = *(const short8*)(const void*)(W2T + (size_t)(cw2 + n * 16 + lr) * HH + ks * 32 + kq * 8);
#pragma unroll
        for (int r = 0; r < 2; ++r)
#pragma unroll
            for (int n = 0; n < 2; ++n)
                acc2[r][n] = __builtin_amdgcn_mfma_f32_16x16x32_bf16(ah[r], bw[n], acc2[r][n], 0, 0, 0);
    }
    __syncthreads();   // all h reads done; safe to overwrite with logits

    // logits -> sLf [32][132]
#pragma unroll
    for (int r = 0; r < 2; ++r)
#pragma unroll
        for (int n = 0; n < 2; ++n)
#pragma unroll
            for (int q = 0; q < 4; ++q) {
                const int row = r * 16 + kq * 4 + q;
                const int col = cw2 + n * 16 + lr;
                sLf[row * 132 + col] = acc2[r][n][q];
            }
    __syncthreads();

    // ---- epilogue ----
    const int tx = tid & 15;   // cols tx*8..+7
    const int ty = tid >> 4;   // rows ty*2, ty*2+1

    float b2v[8];
    {
        const float4 bb0 = *(const float4*)(b2 + tx * 8 + 0);
        const float4 bb1 = *(const float4*)(b2 + tx * 8 + 4);
        b2v[0]=bb0.x; b2v[1]=bb0.y; b2v[2]=bb0.z; b2v[3]=bb0.w;
        b2v[4]=bb1.x; b2v[5]=bb1.y; b2v[6]=bb1.z; b2v[7]=bb1.w;
    }

    float pr[2][8];
    float pmaxv[2];
#pragma unroll
    for (int i = 0; i < 2; ++i) {
        const int row = ty * 2 + i;
        const int s  = s0 + row;
        const int sc = min(s, SS - 1);
        const float* np_ = noise + ((size_t)c * SS + sc) * MM + tx * 8;
        const float4 u0 = *(const float4*)(np_ + 0);
        const float4 u1 = *(const float4*)(np_ + 4);
        const float uu[8] = {u0.x,u0.y,u0.z,u0.w,u1.x,u1.y,u1.z,u1.w};
        float pm[8];
#pragma unroll
        for (int q = 0; q < 8; ++q) {
            const float g = -__logf(-__logf(uu[q] + 1e-20f) + 1e-20f);
            pm[q] = sLf[row * 132 + tx * 8 + q] + b2v[q] + g;
        }
        float mx = pm[0];
#pragma unroll
        for (int q = 1; q < 8; ++q) mx = fmaxf(mx, pm[q]);
        for (int d = 1; d < 16; d <<= 1) mx = fmaxf(mx, __shfl_xor(mx, d, 16));
        float se = 0.0f;
#pragma unroll
        for (int q = 0; q < 8; ++q) { pr[i][q] = __expf(pm[q] - mx); se += pr[i][q]; }
        for (int d = 1; d < 16; d <<= 1) se += __shfl_xor(se, d, 16);
        const float inv = 1.0f / se;
#pragma unroll
        for (int q = 0; q < 8; ++q) pr[i][q] *= inv;
        pmaxv[i] = inv;   // max prob == exp(0)*inv
    }

    // ---- top-K threshold: dual-row packed bisection (20 iters) ----
    // invariant per row: cnt_gt(lo) >= 30, cnt_gt(hi) <= 29; final width ~3e-8
    float lo0 = 0.0f, lo1 = 0.0f;
    float hi0 = fminf(pmaxv[0], 1.0f / 30.0f);
    float hi1 = fminf(pmaxv[1], 1.0f / 30.0f);
    for (int it = 0; it < 20; ++it) {
        const float mid0 = 0.5f * (lo0 + hi0);
        const float mid1 = 0.5f * (lo1 + hi1);
        int cnt = 0;
#pragma unroll
        for (int q = 0; q < 8; ++q) {
            cnt += (pr[0][q] > mid0) ? 1 : 0;
            cnt += (pr[1][q] > mid1) ? 256 : 0;
        }
        for (int d = 1; d < 16; d <<= 1) cnt += __shfl_xor(cnt, d, 16);
        const bool ge0 = (cnt & 255) >= TOPK;
        const bool ge1 = (cnt >> 8)  >= TOPK;
        lo0 = ge0 ? mid0 : lo0;  hi0 = ge0 ? hi0 : mid0;
        lo1 = ge1 ? mid1 : lo1;  hi1 = ge1 ? hi1 : mid1;
    }
    const float thr_[2] = {hi0, hi1};

    // ---- sigmoid gate + mask + store ----
#pragma unroll
    for (int i = 0; i < 2; ++i) {
        const int s = s0 + ty * 2 + i;
        if (s < SS) {
            const float mz = (mask[(size_t)c * LL + s + 1] != 0) ? 0.0f : 1.0f;
            float ov[8];
#pragma unroll
            for (int q = 0; q < 8; ++q) {
                const float sm = 1.0f / (1.0f + __expf((thr_[i] - pr[i][q]) * 100.0f));
                ov[q] = pr[i][q] * sm * mz;
            }
            float* op = out + ((size_t)c * SS + s) * MM + tx * 8;
            float4 o0, o1;
            o0.x=ov[0]; o0.y=ov[1]; o0.z=ov[2]; o0.w=ov[3];
            o1.x=ov[4]; o1.y=ov[5]; o1.z=ov[6]; o1.w=ov[7];
            *(float4*)(op + 0) = o0;
            *(float4*)(op + 4) = o1;
        }
    }

    if (tid < 32) {
        const int s = s0 + tid;
        if (s < SS)
            outk[(size_t)c * SS + s] = (mask[(size_t)c * LL + s + 1] != 0) ? 1.0f : 0.0f;
    }
}

extern "C" void kernel_launch(void* const* d_in, const int* in_sizes, int n_in,
                              void* d_out, int out_size, void* d_ws, size_t ws_size,
                              hipStream_t stream) {
    const float* x     = (const float*)d_in[0];
    const int*   mask  = (const int*)d_in[1];
    const float* noise = (const float*)d_in[2];
    const float* W1    = (const float*)d_in[3];
    const float* b1    = (const float*)d_in[4];
    const float* W2    = (const float*)d_in[5];
    const float* b2    = (const float*)d_in[6];
    float* out  = (float*)d_out;
    float* outk = out + (size_t)CC * SS * MM;

    unsigned short* W1T = (unsigned short*)d_ws;            // 256 x 512 bf16 = 256 KB
    unsigned short* W2T = W1T + (size_t)HH * EE;            // 128 x 256 bf16 =  64 KB

    prep_weights<<<dim3(80), dim3(256), 0, stream>>>(W1, W2, W1T, W2T);

    dim3 grid(256, CC);
    gene_router_kernel<<<grid, dim3(256), 0, stream>>>(x, mask, noise, W1T, b1, W2T, b2, out, outk);
}

// Round 6
// 195.648 us; speedup vs baseline: 1.5256x; 1.5256x over previous
//
#include <hip/hip_runtime.h>
#include <hip/hip_bf16.h>

#define CC 16
#define LL 8192
#define SS 8191   // L-1
#define EE 512
#define HH 256
#define MM 128
#define TOPK 30

typedef __attribute__((ext_vector_type(8))) short short8;
typedef __attribute__((ext_vector_type(4))) float f32x4;
typedef __attribute__((ext_vector_type(4))) unsigned int u32x4;

static __device__ __forceinline__ unsigned short f2bf(float f) {
    unsigned u = __builtin_bit_cast(unsigned, f);
    u += 0x7FFFu + ((u >> 16) & 1u);   // RNE
    return (unsigned short)(u >> 16);
}

static __device__ __forceinline__ unsigned pk2(float lo, float hi) {
    __hip_bfloat162 t = __float22bfloat162_rn(float2{lo, hi});
    unsigned u;
    __builtin_memcpy(&u, &t, 4);
    return u;
}

// 8 f32 -> 8 bf16 (v_cvt_pk_bf16_f32)
static __device__ __forceinline__ short8 cvt8(const float4 a, const float4 b) {
    u32x4 uv;
    uv[0] = pk2(a.x, a.y);
    uv[1] = pk2(a.z, a.w);
    uv[2] = pk2(b.x, b.y);
    uv[3] = pk2(b.z, b.w);
    return __builtin_bit_cast(short8, uv);
}

// ---- DPP row_ror reduces over 16-lane groups (VALU pipe, no LDS latency) ----
template<int CTRL>
static __device__ __forceinline__ float dppf(float v) {
    return __builtin_bit_cast(float,
        __builtin_amdgcn_update_dpp(0, __builtin_bit_cast(int, v), CTRL, 0xF, 0xF, false));
}
template<int CTRL>
static __device__ __forceinline__ int dppi(int v) {
    return __builtin_amdgcn_update_dpp(0, v, CTRL, 0xF, 0xF, false);
}
static __device__ __forceinline__ float sum16f(float v) {
    v += dppf<0x121>(v); v += dppf<0x122>(v); v += dppf<0x124>(v); v += dppf<0x128>(v);
    return v;
}
static __device__ __forceinline__ float max16f(float v) {
    v = fmaxf(v, dppf<0x121>(v)); v = fmaxf(v, dppf<0x122>(v));
    v = fmaxf(v, dppf<0x124>(v)); v = fmaxf(v, dppf<0x128>(v));
    return v;
}
static __device__ __forceinline__ int sum16i(int v) {
    v += dppi<0x121>(v); v += dppi<0x122>(v); v += dppi<0x124>(v); v += dppi<0x128>(v);
    return v;
}

// ---------------- prep: W1 (E x H) -> W1T bf16 (H x E); W2 (H x M) -> W2T bf16 (M x H)
__global__ void prep_weights(const float* __restrict__ W1, const float* __restrict__ W2,
                             unsigned short* __restrict__ W1T, unsigned short* __restrict__ W2T)
{
    const int b = blockIdx.x, tid = threadIdx.x;
    if (b < 64) {
        const int e0 = b * 8, h = tid;
        short8 sv;
#pragma unroll
        for (int j = 0; j < 8; ++j)
            sv[j] = (short)f2bf(W1[(size_t)(e0 + j) * HH + h]);
        *(short8*)(void*)(W1T + (size_t)h * EE + e0) = sv;
    } else {
        const int h0 = (b - 64) * 16;
        if (tid < MM) {
            const int m = tid;
            short8 s0v, s1v;
#pragma unroll
            for (int j = 0; j < 8; ++j) {
                s0v[j] = (short)f2bf(W2[(size_t)(h0 + j) * MM + m]);
                s1v[j] = (short)f2bf(W2[(size_t)(h0 + 8 + j) * MM + m]);
            }
            *(short8*)(void*)(W2T + (size_t)m * HH + h0) = s0v;
            *(short8*)(void*)(W2T + (size_t)m * HH + h0 + 8) = s1v;
        }
    }
}

// ---------------- fused main kernel: 32 rows/block, 256 threads (4 waves)
// LDS 32 KB: [0,16K) x-half0 bf16 -> h bf16 -> logits part 1
//            [16K,32K) x-half1 bf16 -> logits tail
__global__ __launch_bounds__(256, 4)
void gene_router_kernel(const float* __restrict__ x,
                        const int*   __restrict__ mask,
                        const float* __restrict__ noise,
                        const unsigned short* __restrict__ W1T,
                        const float* __restrict__ b1,
                        const unsigned short* __restrict__ W2T,
                        const float* __restrict__ b2,
                        float* __restrict__ out,
                        float* __restrict__ outk)
{
    __shared__ __align__(16) unsigned char lds[32768];
    float* sLf = (float*)lds;                      // logits f32 [32][132] overlay

    const int tid = threadIdx.x;
    const int c   = blockIdx.y;
    const int s0  = blockIdx.x * 32;

    const int w    = tid >> 6;      // wave 0..3
    const int lane = tid & 63;
    const int lr   = lane & 15;
    const int kq   = lane >> 4;
    const int tx   = tid & 15;      // epilogue cols tx*8..+7
    const int ty   = tid >> 4;      // epilogue rows ty*2, ty*2+1

    // ---- outk early (independent) ----
    if (tid < 32) {
        const int s = s0 + tid;
        if (s < SS)
            outk[(size_t)c * SS + s] = (mask[(size_t)c * LL + s + 1] != 0) ? 1.0f : 0.0f;
    }

    // ---- stage x half0 (cols 0..255) f32->bf16 swizzled ----
    const float* xb = x + ((size_t)c * LL + s0 + 1) * EE;
    const int rowA = tid >> 5;      // 0..7
    const int cu   = tid & 31;      // 8-col unit within half
#pragma unroll
    for (int it = 0; it < 4; ++it) {
        const int row = it * 8 + rowA;
        const int rs  = min(s0 + row, SS - 1) - s0;
        const float* p = xb + (size_t)rs * EE + cu * 8;
        const float4 a = *(const float4*)p;
        const float4 b = *(const float4*)(p + 4);
        *(short8*)(void*)(lds + row * 512 + ((cu * 16) ^ ((row & 7) << 4))) = cvt8(a, b);
    }
    __syncthreads();   // bar1: half0 visible

    // ---- issue half1 global loads NOW (hide under GEMM1-half0) ----
    float4 rB[4][2];
#pragma unroll
    for (int it = 0; it < 4; ++it) {
        const int row = it * 8 + rowA;
        const int rs  = min(s0 + row, SS - 1) - s0;
        const float* p = xb + (size_t)rs * EE + 256 + cu * 8;
        rB[it][0] = *(const float4*)p;
        rB[it][1] = *(const float4*)(p + 4);
    }

    const int cw = w * 64;
    float b1v[4];
#pragma unroll
    for (int n = 0; n < 4; ++n) b1v[n] = b1[cw + n * 16 + lr];

    // ---- GEMM1 half0: ks 0..7 ----
    f32x4 acc[2][4];
#pragma unroll
    for (int r = 0; r < 2; ++r)
#pragma unroll
        for (int n = 0; n < 4; ++n) acc[r][n] = (f32x4)0.0f;

#pragma unroll 4
    for (int ks2 = 0; ks2 < 8; ++ks2) {
        short8 af[2];
#pragma unroll
        for (int r = 0; r < 2; ++r) {
            const int row = r * 16 + lr;
            af[r] = *(const short8*)(const void*)(lds + row * 512
                        + ((ks2 * 64 + kq * 16) ^ ((row & 7) << 4)));
        }
        short8 bf_[4];
#pragma unroll
        for (int n = 0; n < 4; ++n)
            bf_[n] = *(const short8*)(const void*)(W1T + (size_t)(cw + n * 16 + lr) * EE + ks2 * 32 + kq * 8);
#pragma unroll
        for (int r = 0; r < 2; ++r)
#pragma unroll
            for (int n = 0; n < 4; ++n)
                acc[r][n] = __builtin_amdgcn_mfma_f32_16x16x32_bf16(af[r], bf_[n], acc[r][n], 0, 0, 0);
    }

    // ---- write half1 to LDS (loads already landed during GEMM1-half0) ----
#pragma unroll
    for (int it = 0; it < 4; ++it) {
        const int row = it * 8 + rowA;
        *(short8*)(void*)(lds + 16384 + row * 512 + ((cu * 16) ^ ((row & 7) << 4)))
            = cvt8(rB[it][0], rB[it][1]);
    }
    __syncthreads();   // bar2: half1 visible; all half0 reads done

    // ---- prefetch epilogue inputs (hide under GEMM1-half1 + GEMM2) ----
    float4 nz[2][2];
    int mk[2];
#pragma unroll
    for (int i = 0; i < 2; ++i) {
        const int s  = s0 + ty * 2 + i;
        const int sc = min(s, SS - 1);
        const float* np_ = noise + ((size_t)c * SS + sc) * MM + tx * 8;
        nz[i][0] = *(const float4*)np_;
        nz[i][1] = *(const float4*)(np_ + 4);
        mk[i] = mask[(size_t)c * LL + sc + 1];
    }
    const float4 b2a = *(const float4*)(b2 + tx * 8);
    const float4 b2b = *(const float4*)(b2 + tx * 8 + 4);

    // ---- GEMM1 half1: ks 8..15 ----
#pragma unroll 4
    for (int ks2 = 0; ks2 < 8; ++ks2) {
        short8 af[2];
#pragma unroll
        for (int r = 0; r < 2; ++r) {
            const int row = r * 16 + lr;
            af[r] = *(const short8*)(const void*)(lds + 16384 + row * 512
                        + ((ks2 * 64 + kq * 16) ^ ((row & 7) << 4)));
        }
        short8 bf_[4];
#pragma unroll
        for (int n = 0; n < 4; ++n)
            bf_[n] = *(const short8*)(const void*)(W1T + (size_t)(cw + n * 16 + lr) * EE + (8 + ks2) * 32 + kq * 8);
#pragma unroll
        for (int r = 0; r < 2; ++r)
#pragma unroll
            for (int n = 0; n < 4; ++n)
                acc[r][n] = __builtin_amdgcn_mfma_f32_16x16x32_bf16(af[r], bf_[n], acc[r][n], 0, 0, 0);
    }

    // ---- bias + relu -> h bf16 (swizzled) in [0,16K) ----
#pragma unroll
    for (int n = 0; n < 4; ++n) {
        const int colh = cw + n * 16 + lr;
#pragma unroll
        for (int r = 0; r < 2; ++r)
#pragma unroll
            for (int q = 0; q < 4; ++q) {
                const int row = r * 16 + kq * 4 + q;
                const unsigned short hv = f2bf(fmaxf(acc[r][n][q] + b1v[n], 0.0f));
                *(unsigned short*)(lds + row * 512 + ((colh * 2) ^ ((row & 7) << 4))) = hv;
            }
    }
    __syncthreads();   // bar3: h visible

    // ---- GEMM2: logits[32][128] = h @ W2 ----
    f32x4 acc2[2][2];
#pragma unroll
    for (int r = 0; r < 2; ++r)
#pragma unroll
        for (int n = 0; n < 2; ++n) acc2[r][n] = (f32x4)0.0f;

    const int cw2 = w * 32;
#pragma unroll 4
    for (int ks = 0; ks < 8; ++ks) {
        short8 ah[2];
#pragma unroll
        for (int r = 0; r < 2; ++r) {
            const int row = r * 16 + lr;
            ah[r] = *(const short8*)(const void*)(lds + row * 512
                        + ((ks * 64 + kq * 16) ^ ((row & 7) << 4)));
        }
        short8 bw[2];
#pragma unroll
        for (int n = 0; n < 2; ++n)
            bw[n] = *(const short8*)(const void*)(W2T + (size_t)(cw2 + n * 16 + lr) * HH + ks * 32 + kq * 8);
#pragma unroll
        for (int r = 0; r < 2; ++r)
#pragma unroll
            for (int n = 0; n < 2; ++n)
                acc2[r][n] = __builtin_amdgcn_mfma_f32_16x16x32_bf16(ah[r], bw[n], acc2[r][n], 0, 0, 0);
    }
    __syncthreads();   // bar4: all h reads done; overlay logits

    // ---- logits -> sLf [32][132] ----
#pragma unroll
    for (int r = 0; r < 2; ++r)
#pragma unroll
        for (int n = 0; n < 2; ++n)
#pragma unroll
            for (int q = 0; q < 4; ++q) {
                const int row = r * 16 + kq * 4 + q;
                const int col = cw2 + n * 16 + lr;
                sLf[row * 132 + col] = acc2[r][n][q];
            }
    __syncthreads();   // bar5

    // ---- epilogue: gumbel + softmax (DPP reduces) ----
    float b2v[8] = {b2a.x, b2a.y, b2a.z, b2a.w, b2b.x, b2b.y, b2b.z, b2b.w};

    float pr[2][8];
    float pmaxv[2];
#pragma unroll
    for (int i = 0; i < 2; ++i) {
        const int row = ty * 2 + i;
        const float uu[8] = {nz[i][0].x, nz[i][0].y, nz[i][0].z, nz[i][0].w,
                             nz[i][1].x, nz[i][1].y, nz[i][1].z, nz[i][1].w};
        const float4 l0 = *(const float4*)&sLf[row * 132 + tx * 8];
        const float4 l1 = *(const float4*)&sLf[row * 132 + tx * 8 + 4];
        const float lg[8] = {l0.x, l0.y, l0.z, l0.w, l1.x, l1.y, l1.z, l1.w};
        float pm[8];
#pragma unroll
        for (int q = 0; q < 8; ++q) {
            const float g = -__logf(-__logf(uu[q] + 1e-20f) + 1e-20f);
            pm[q] = lg[q] + b2v[q] + g;
        }
        float mx = pm[0];
#pragma unroll
        for (int q = 1; q < 8; ++q) mx = fmaxf(mx, pm[q]);
        mx = max16f(mx);
        float se = 0.0f;
#pragma unroll
        for (int q = 0; q < 8; ++q) { pr[i][q] = __expf(pm[q] - mx); se += pr[i][q]; }
        se = sum16f(se);
        const float inv = 1.0f / se;
#pragma unroll
        for (int q = 0; q < 8; ++q) pr[i][q] *= inv;
        pmaxv[i] = inv;   // max prob == exp(0)*inv
    }

    // ---- top-K threshold: dual-row packed bisection, 16 iters, DPP count ----
    float lo0 = 0.0f, lo1 = 0.0f;
    float hi0 = fminf(pmaxv[0], 1.0f / 30.0f);
    float hi1 = fminf(pmaxv[1], 1.0f / 30.0f);
    for (int it = 0; it < 16; ++it) {
        const float mid0 = 0.5f * (lo0 + hi0);
        const float mid1 = 0.5f * (lo1 + hi1);
        int cnt = 0;
#pragma unroll
        for (int q = 0; q < 8; ++q) {
            cnt += (pr[0][q] > mid0) ? 1 : 0;
            cnt += (pr[1][q] > mid1) ? 256 : 0;
        }
        cnt = sum16i(cnt);
        const bool ge0 = (cnt & 255) >= TOPK;
        const bool ge1 = (cnt >> 8)  >= TOPK;
        lo0 = ge0 ? mid0 : lo0;  hi0 = ge0 ? hi0 : mid0;
        lo1 = ge1 ? mid1 : lo1;  hi1 = ge1 ? hi1 : mid1;
    }
    const float thr_[2] = {hi0, hi1};

    // ---- sigmoid gate + mask + store ----
#pragma unroll
    for (int i = 0; i < 2; ++i) {
        const int s = s0 + ty * 2 + i;
        if (s < SS) {
            const float mz = (mk[i] != 0) ? 0.0f : 1.0f;
            float ov[8];
#pragma unroll
            for (int q = 0; q < 8; ++q) {
                const float sm = 1.0f / (1.0f + __expf((thr_[i] - pr[i][q]) * 100.0f));
                ov[q] = pr[i][q] * sm * mz;
            }
            float* op = out + ((size_t)c * SS + s) * MM + tx * 8;
            float4 o0, o1;
            o0.x=ov[0]; o0.y=ov[1]; o0.z=ov[2]; o0.w=ov[3];
            o1.x=ov[4]; o1.y=ov[5]; o1.z=ov[6]; o1.w=ov[7];
            *(float4*)(op + 0) = o0;
            *(float4*)(op + 4) = o1;
        }
    }
}

extern "C" void kernel_launch(void* const* d_in, const int* in_sizes, int n_in,
                              void* d_out, int out_size, void* d_ws, size_t ws_size,
                              hipStream_t stream) {
    const float* x     = (const float*)d_in[0];
    const int*   mask  = (const int*)d_in[1];
    const float* noise = (const float*)d_in[2];
    const float* W1    = (const float*)d_in[3];
    const float* b1    = (const float*)d_in[4];
    const float* W2    = (const float*)d_in[5];
    const float* b2    = (const float*)d_in[6];
    float* out  = (float*)d_out;
    float* outk = out + (size_t)CC * SS * MM;

    unsigned short* W1T = (unsigned short*)d_ws;            // 256 x 512 bf16 = 256 KB
    unsigned short* W2T = W1T + (size_t)HH * EE;            // 128 x 256 bf16 =  64 KB

    prep_weights<<<dim3(80), dim3(256), 0, stream>>>(W1, W2, W1T, W2T);

    dim3 grid(256, CC);
    gene_router_kernel<<<grid, dim3(256), 0, stream>>>(x, mask, noise, W1T, b1, W2T, b2, out, outk);
}

// Round 7
// 180.982 us; speedup vs baseline: 1.6493x; 1.0810x over previous
//
#include <hip/hip_runtime.h>
#include <hip/hip_bf16.h>

#define CC 16
#define LL 8192
#define SS 8191   // L-1
#define EE 512
#define HH 256
#define MM 128
#define TOPK 30

typedef __attribute__((ext_vector_type(8))) short short8;
typedef __attribute__((ext_vector_type(4))) float f32x4;
typedef __attribute__((ext_vector_type(4))) unsigned int u32x4;

static __device__ __forceinline__ unsigned short f2bf(float f) {
    unsigned u = __builtin_bit_cast(unsigned, f);
    u += 0x7FFFu + ((u >> 16) & 1u);   // RNE
    return (unsigned short)(u >> 16);
}

static __device__ __forceinline__ unsigned pk2(float lo, float hi) {
    __hip_bfloat162 t = __float22bfloat162_rn(float2{lo, hi});
    unsigned u;
    __builtin_memcpy(&u, &t, 4);
    return u;
}

// 8 f32 -> 8 bf16 (v_cvt_pk_bf16_f32)
static __device__ __forceinline__ short8 cvt8(const float4 a, const float4 b) {
    u32x4 uv;
    uv[0] = pk2(a.x, a.y);
    uv[1] = pk2(a.z, a.w);
    uv[2] = pk2(b.x, b.y);
    uv[3] = pk2(b.z, b.w);
    return __builtin_bit_cast(short8, uv);
}

// async global->LDS, 16B per lane (global_load_lds_dwordx4)
static __device__ __forceinline__ void gl2lds16(const float* g, unsigned char* l) {
    __builtin_amdgcn_global_load_lds(
        (const __attribute__((address_space(1))) void*)g,
        (__attribute__((address_space(3))) void*)l,
        16, 0, 0);
}

// ---- DPP row_ror reduces over 16-lane groups ----
template<int CTRL>
static __device__ __forceinline__ float dppf(float v) {
    return __builtin_bit_cast(float,
        __builtin_amdgcn_update_dpp(0, __builtin_bit_cast(int, v), CTRL, 0xF, 0xF, false));
}
template<int CTRL>
static __device__ __forceinline__ int dppi(int v) {
    return __builtin_amdgcn_update_dpp(0, v, CTRL, 0xF, 0xF, false);
}
static __device__ __forceinline__ float sum16f(float v) {
    v += dppf<0x121>(v); v += dppf<0x122>(v); v += dppf<0x124>(v); v += dppf<0x128>(v);
    return v;
}
static __device__ __forceinline__ float max16f(float v) {
    v = fmaxf(v, dppf<0x121>(v)); v = fmaxf(v, dppf<0x122>(v));
    v = fmaxf(v, dppf<0x124>(v)); v = fmaxf(v, dppf<0x128>(v));
    return v;
}
static __device__ __forceinline__ unsigned sum16u(unsigned v) {
    v += (unsigned)dppi<0x121>((int)v); v += (unsigned)dppi<0x122>((int)v);
    v += (unsigned)dppi<0x124>((int)v); v += (unsigned)dppi<0x128>((int)v);
    return v;
}

// ---------------- prep: W1 (E x H) -> W1T bf16 (H x E); W2 (H x M) -> W2T bf16 (M x H)
__global__ void prep_weights(const float* __restrict__ W1, const float* __restrict__ W2,
                             unsigned short* __restrict__ W1T, unsigned short* __restrict__ W2T)
{
    const int b = blockIdx.x, tid = threadIdx.x;
    if (b < 64) {
        const int e0 = b * 8, h = tid;
        short8 sv;
#pragma unroll
        for (int j = 0; j < 8; ++j)
            sv[j] = (short)f2bf(W1[(size_t)(e0 + j) * HH + h]);
        *(short8*)(void*)(W1T + (size_t)h * EE + e0) = sv;
    } else {
        const int h0 = (b - 64) * 16;
        if (tid < MM) {
            const int m = tid;
            short8 s0v, s1v;
#pragma unroll
            for (int j = 0; j < 8; ++j) {
                s0v[j] = (short)f2bf(W2[(size_t)(h0 + j) * MM + m]);
                s1v[j] = (short)f2bf(W2[(size_t)(h0 + 8 + j) * MM + m]);
            }
            *(short8*)(void*)(W2T + (size_t)m * HH + h0) = s0v;
            *(short8*)(void*)(W2T + (size_t)m * HH + h0 + 8) = s1v;
        }
    }
}

// ---------------- fused main: 128 rows/block, 512 threads (8 waves, 2Mrow x 4Ncol)
// LDS 64 KB: two 32KB x-chunk buffers (f32, K=64 each, source-permuted) ->
//            h bf16 [128][256] swizzled -> logits f32 [128][128] swizzled.
__global__ __launch_bounds__(512, 4)
void gene_router_kernel(const float* __restrict__ x,
                        const int*   __restrict__ mask,
                        const float* __restrict__ noise,
                        const unsigned short* __restrict__ W1T,
                        const float* __restrict__ b1,
                        const unsigned short* __restrict__ W2T,
                        const float* __restrict__ b2,
                        float* __restrict__ out,
                        float* __restrict__ outk)
{
    __shared__ __align__(16) unsigned char lds[65536];

    const int tid = threadIdx.x;
    const int c   = blockIdx.y;
    const int s0  = blockIdx.x * 128;

    const int w    = tid >> 6;      // wave 0..7
    const int lane = tid & 63;
    const int lr   = lane & 15;
    const int kq   = lane >> 4;
    const int wr   = w >> 2;        // 0..1 (row half)
    const int wc   = w & 3;         // 0..3 (col quarter)
    const int tx   = tid & 15;
    const int ty   = tid >> 4;      // 0..31

    // ---- outk early ----
    if (tid < 128) {
        const int s = s0 + tid;
        if (s < SS)
            outk[(size_t)c * SS + s] = (mask[(size_t)c * LL + s + 1] != 0) ? 1.0f : 0.0f;
    }

    const float* xb = x + ((size_t)c * LL + s0 + 1) * EE;

    // stage chunk ck -> LDS at bufoff. per thread 4x gl2lds16.
    // LDS unit (row, cu) holds global f32 unit (cu ^ (row&7)) of the chunk.
#define STAGE(ck, bufoff) do {                                              \
    _Pragma("unroll")                                                       \
    for (int it_ = 0; it_ < 4; ++it_) {                                     \
        const int row_ = it_ * 32 + ty;                                     \
        const int rs_  = min(s0 + row_, SS - 1) - s0;                       \
        const float* g_ = xb + (size_t)rs_ * EE + (ck) * 64                 \
                          + ((tx ^ (row_ & 7)) << 2);                       \
        gl2lds16(g_, lds + (bufoff) + (it_ * 512 + tid) * 16);              \
    } } while (0)

    const int cw = wc * 64;
    float b1v[4];
#pragma unroll
    for (int n = 0; n < 4; ++n) b1v[n] = b1[cw + n * 16 + lr];

    // ---- GEMM1: h[128][256] = relu(xs @ W1 + b1), K chunked 8x64, dbuf ----
    f32x4 acc[4][4];
#pragma unroll
    for (int r = 0; r < 4; ++r)
#pragma unroll
        for (int n = 0; n < 4; ++n) acc[r][n] = (f32x4)0.0f;

    STAGE(0, 0);
    __syncthreads();

    for (int ck = 0; ck < 8; ++ck) {
        const int cur = (ck & 1) << 15;
        if (ck < 7) STAGE(ck + 1, ((ck + 1) & 1) << 15);
#pragma unroll
        for (int ks = 0; ks < 2; ++ks) {
            short8 af[4];
#pragma unroll
            for (int r = 0; r < 4; ++r) {
                const int row = wr * 64 + r * 16 + lr;
                const int ug  = ks * 8 + kq * 2;
                const float4 a0 = *(const float4*)(const void*)
                    (lds + cur + row * 256 + (((ug + 0) ^ (row & 7)) << 4));
                const float4 a1 = *(const float4*)(const void*)
                    (lds + cur + row * 256 + (((ug + 1) ^ (row & 7)) << 4));
                af[r] = cvt8(a0, a1);
            }
            short8 bf_[4];
#pragma unroll
            for (int n = 0; n < 4; ++n)
                bf_[n] = *(const short8*)(const void*)
                    (W1T + (size_t)(cw + n * 16 + lr) * EE + ck * 64 + ks * 32 + kq * 8);
#pragma unroll
            for (int r = 0; r < 4; ++r)
#pragma unroll
                for (int n = 0; n < 4; ++n)
                    acc[r][n] = __builtin_amdgcn_mfma_f32_16x16x32_bf16(af[r], bf_[n], acc[r][n], 0, 0, 0);
        }
        __syncthreads();   // chunk ck+1 staged & visible; all ck reads done
    }

    // ---- bias + relu -> h bf16 [128][256] swizzled (overlays both buffers) ----
#pragma unroll
    for (int n = 0; n < 4; ++n) {
        const int colh = cw + n * 16 + lr;
#pragma unroll
        for (int r = 0; r < 4; ++r)
#pragma unroll
            for (int q = 0; q < 4; ++q) {
                const int row = wr * 64 + r * 16 + kq * 4 + q;
                *(unsigned short*)(lds + row * 512 + ((colh * 2) ^ ((row & 7) << 4))) =
                    f2bf(fmaxf(acc[r][n][q] + b1v[n], 0.0f));
            }
    }
    __syncthreads();

    // ---- prefetch epilogue inputs (land during GEMM2) ----
    float4 nz[4][2];
    int mk[4];
#pragma unroll
    for (int i = 0; i < 4; ++i) {
        const int s  = s0 + ty * 4 + i;
        const int sc = min(s, SS - 1);
        const float* np_ = noise + ((size_t)c * SS + sc) * MM + tx * 8;
        nz[i][0] = *(const float4*)np_;
        nz[i][1] = *(const float4*)(np_ + 4);
        mk[i] = mask[(size_t)c * LL + sc + 1];
    }
    const float4 b2a = *(const float4*)(b2 + tx * 8);
    const float4 b2b = *(const float4*)(b2 + tx * 8 + 4);

    // ---- GEMM2: logits[128][128] = h @ W2 ----
    f32x4 acc2[4][2];
#pragma unroll
    for (int r = 0; r < 4; ++r)
#pragma unroll
        for (int n = 0; n < 2; ++n) acc2[r][n] = (f32x4)0.0f;

    const int cw2 = wc * 32;
#pragma unroll 4
    for (int ks = 0; ks < 8; ++ks) {
        short8 ah[4];
#pragma unroll
        for (int r = 0; r < 4; ++r) {
            const int row = wr * 64 + r * 16 + lr;
            ah[r] = *(const short8*)(const void*)
                (lds + row * 512 + ((ks * 64 + kq * 16) ^ ((row & 7) << 4)));
        }
        short8 bw[2];
#pragma unroll
        for (int n = 0; n < 2; ++n)
            bw[n] = *(const short8*)(const void*)
                (W2T + (size_t)(cw2 + n * 16 + lr) * HH + ks * 32 + kq * 8);
#pragma unroll
        for (int r = 0; r < 4; ++r)
#pragma unroll
            for (int n = 0; n < 2; ++n)
                acc2[r][n] = __builtin_amdgcn_mfma_f32_16x16x32_bf16(ah[r], bw[n], acc2[r][n], 0, 0, 0);
    }
    __syncthreads();   // all h reads done; overlay logits

    // ---- logits f32 [128][128] swizzled into same region ----
#pragma unroll
    for (int r = 0; r < 4; ++r)
#pragma unroll
        for (int n = 0; n < 2; ++n)
#pragma unroll
            for (int q = 0; q < 4; ++q) {
                const int row = wr * 64 + r * 16 + kq * 4 + q;
                const int col = cw2 + n * 16 + lr;
                *(float*)(lds + row * 512
                          + ((((col >> 2) << 4) ^ ((row & 7) << 4)) | ((col & 3) << 2)))
                    = acc2[r][n][q];
            }
    __syncthreads();

    // ---- epilogue: 4 rows/thread ----
    float b2v[8] = {b2a.x, b2a.y, b2a.z, b2a.w, b2b.x, b2b.y, b2b.z, b2b.w};

    float pr[4][8];
    float pmaxv[4];
#pragma unroll
    for (int i = 0; i < 4; ++i) {
        const int row = ty * 4 + i;
        const float4 l0 = *(const float4*)(const void*)
            (lds + row * 512 + ((tx * 32) ^ ((row & 7) << 4)));
        const float4 l1 = *(const float4*)(const void*)
            (lds + row * 512 + ((tx * 32 + 16) ^ ((row & 7) << 4)));
        const float lg[8] = {l0.x, l0.y, l0.z, l0.w, l1.x, l1.y, l1.z, l1.w};
        const float uu[8] = {nz[i][0].x, nz[i][0].y, nz[i][0].z, nz[i][0].w,
                             nz[i][1].x, nz[i][1].y, nz[i][1].z, nz[i][1].w};
        float pm[8];
#pragma unroll
        for (int q = 0; q < 8; ++q) {
            const float g = -__logf(-__logf(uu[q] + 1e-20f) + 1e-20f);
            pm[q] = lg[q] + b2v[q] + g;
        }
        float mx = pm[0];
#pragma unroll
        for (int q = 1; q < 8; ++q) mx = fmaxf(mx, pm[q]);
        mx = max16f(mx);
        float se = 0.0f;
#pragma unroll
        for (int q = 0; q < 8; ++q) { pr[i][q] = __expf(pm[q] - mx); se += pr[i][q]; }
        se = sum16f(se);
        const float inv = 1.0f / se;
#pragma unroll
        for (int q = 0; q < 8; ++q) pr[i][q] *= inv;
        pmaxv[i] = inv;   // max prob == exp(0)*inv
    }

    // ---- top-K threshold: 4-row packed bisection, 16 iters ----
    float lo[4], hi[4];
#pragma unroll
    for (int i = 0; i < 4; ++i) { lo[i] = 0.0f; hi[i] = fminf(pmaxv[i], 1.0f / 30.0f); }
    for (int it = 0; it < 16; ++it) {
        float mid[4];
#pragma unroll
        for (int i = 0; i < 4; ++i) mid[i] = 0.5f * (lo[i] + hi[i]);
        unsigned cnt = 0;
#pragma unroll
        for (int q = 0; q < 8; ++q) {
            cnt += (pr[0][q] > mid[0]) ? 1u : 0u;
            cnt += (pr[1][q] > mid[1]) ? (1u << 8) : 0u;
            cnt += (pr[2][q] > mid[2]) ? (1u << 16) : 0u;
            cnt += (pr[3][q] > mid[3]) ? (1u << 24) : 0u;
        }
        cnt = sum16u(cnt);
#pragma unroll
        for (int i = 0; i < 4; ++i) {
            const bool ge = ((cnt >> (8 * i)) & 255u) >= TOPK;
            lo[i] = ge ? mid[i] : lo[i];
            hi[i] = ge ? hi[i] : mid[i];
        }
    }

    // ---- sigmoid gate + mask + store ----
#pragma unroll
    for (int i = 0; i < 4; ++i) {
        const int s = s0 + ty * 4 + i;
        if (s < SS) {
            const float mz = (mk[i] != 0) ? 0.0f : 1.0f;
            float ov[8];
#pragma unroll
            for (int q = 0; q < 8; ++q) {
                const float sm = 1.0f / (1.0f + __expf((hi[i] - pr[i][q]) * 100.0f));
                ov[q] = pr[i][q] * sm * mz;
            }
            float* op = out + ((size_t)c * SS + s) * MM + tx * 8;
            float4 o0, o1;
            o0.x=ov[0]; o0.y=ov[1]; o0.z=ov[2]; o0.w=ov[3];
            o1.x=ov[4]; o1.y=ov[5]; o1.z=ov[6]; o1.w=ov[7];
            *(float4*)(op + 0) = o0;
            *(float4*)(op + 4) = o1;
        }
    }
#undef STAGE
}

extern "C" void kernel_launch(void* const* d_in, const int* in_sizes, int n_in,
                              void* d_out, int out_size, void* d_ws, size_t ws_size,
                              hipStream_t stream) {
    const float* x     = (const float*)d_in[0];
    const int*   mask  = (const int*)d_in[1];
    const float* noise = (const float*)d_in[2];
    const float* W1    = (const float*)d_in[3];
    const float* b1    = (const float*)d_in[4];
    const float* W2    = (const float*)d_in[5];
    const float* b2    = (const float*)d_in[6];
    float* out  = (float*)d_out;
    float* outk = out + (size_t)CC * SS * MM;

    unsigned short* W1T = (unsigned short*)d_ws;            // 256 x 512 bf16 = 256 KB
    unsigned short* W2T = W1T + (size_t)HH * EE;            // 128 x 256 bf16 =  64 KB

    prep_weights<<<dim3(80), dim3(256), 0, stream>>>(W1, W2, W1T, W2T);

    dim3 grid(64, CC);   // 64 blocks x 128 rows = 8192 >= 8191
    gene_router_kernel<<<grid, dim3(512), 0, stream>>>(x, mask, noise, W1T, b1, W2T, b2, out, outk);
}